// Round 3
// baseline (1367.782 us; speedup 1.0000x reference)
//
#include <hip/hip_runtime.h>
#include <hip/hip_bf16.h>

// ---------------------------------------------------------------------------
// GatedEquivariantBlock: 32x0e+16x1o+8x2e node feats, 0e+1o+2e edge sh.
// Pipeline:
//   K0 w3j_kernel : compute real Wigner-3j tensors (exact port of reference
//                   _cg/_q/_w3j in fp64) -> ws
//   K1 prep_w3r   : W3R[col][c] = W3[c][col], c=64 row = b3 (pad to 68)
//   K2 mlp_kernel : h2T[c][e] = silu(silu(r@W1+b1)@W2+b2), transposed layout
//   memset agg
//   K3 edge_kernel: per 64-edge block: gather x/sh, h2 in VGPRs (lane=edge),
//                   stream W3R via wave-uniform scalar loads, TP into LDS acc,
//                   global atomic scatter into agg[dst]
//   K4 out_kernel : block-diagonal o3.Linear (1/sqrt(M)) + residual
// ---------------------------------------------------------------------------

#define E_PADC 68  // padded row length of W3R (64 weights + b3 + 3 pad)

namespace pt {
constexpr int I1[11]  = {0,0,0,1,1,1,1,2,2,2,2};
constexpr int I2[11]  = {0,1,2,0,1,1,2,0,1,2,2};
constexpr int I3[11]  = {0,1,2,1,0,2,1,2,1,0,2};
constexpr int COL[11] = {0,1024,1536,1792,2048,2560,2688,2944,3008,3136,3392};
constexpr int W3JO[11]= {0,1,10,35,44,53,98,143,168,213,238};
constexpr int MUL[3]  = {32,16,8};
constexpr int FOF[3]  = {0,32,80};   // FEAT_OFFS
constexpr int SOF[3]  = {0,1,4};     // SH_OFFS
constexpr int OOF[3]  = {0,32,80};   // output slot offsets
}

__device__ __constant__ int PC_L1[11] = {0,0,0,1,1,1,1,2,2,2,2};
__device__ __constant__ int PC_L2[11] = {0,1,2,0,1,1,2,0,1,2,2};
__device__ __constant__ int PC_L3[11] = {0,1,2,1,0,2,1,2,1,0,2};
__device__ __constant__ int PC_W3J[11]= {0,1,10,35,44,53,98,143,168,213,238};
__device__ __constant__ double FACT[8] = {1.,1.,2.,6.,24.,120.,720.,5040.};

// ------------------------- K0: Wigner 3j (fp64) ----------------------------
__device__ double cg_coef(int j1,int m1,int j2,int m2,int j3,int m3){
  if (m1+m2 != m3) return 0.0;
  double pref = (double)(2*j3+1)
    * FACT[j1+j2-j3]*FACT[j1-j2+j3]*FACT[-j1+j2+j3]/FACT[j1+j2+j3+1];
  pref *= FACT[j1+m1]*FACT[j1-m1]*FACT[j2+m2]*FACT[j2-m2]*FACT[j3+m3]*FACT[j3-m3];
  int k0 = 0;
  if (j2-j3-m1 > k0) k0 = j2-j3-m1;
  if (j1-j3+m2 > k0) k0 = j1-j3+m2;
  int k1 = j1+j2-j3;
  if (j1-m1 < k1) k1 = j1-m1;
  if (j2+m2 < k1) k1 = j2+m2;
  double s = 0.0;
  for (int k=k0;k<=k1;++k){
    double d = FACT[k]*FACT[j1+j2-j3-k]*FACT[j1-m1-k]*FACT[j2+m2-k]
             * FACT[j3-j2+m1+k]*FACT[j3-j1-m2+k];
    s += ((k&1)? -1.0: 1.0)/d;
  }
  return sqrt(pref)*s;
}

// q[r][c] for given l, e3nn real->complex basis, includes (-i)^l factor
__device__ void qval(int l, int r, int c, double& qr, double& qi){
  const double inv = 0.70710678118654752440;
  int m = r - l;
  double a=0.0, b=0.0;
  if (m < 0){
    if (c == l - m) a = inv;     // col l+|m|
    if (c == l + m) b = -inv;    // col l-|m|
  } else if (m == 0){
    if (c == l) a = 1.0;
  } else {
    double s = (m & 1) ? -1.0 : 1.0;
    if (c == l + m) a = s*inv;
    if (c == l - m) b = s*inv;
  }
  if (l == 1){ double t=a; a=b; b=-t; }   // * (-i)
  else if (l == 2){ a=-a; b=-b; }         // * (-1)
  qr=a; qi=b;
}

__global__ void w3j_kernel(float* __restrict__ w3jbuf){
  int p = blockIdx.x;
  int l1 = PC_L1[p], l2 = PC_L2[p], l3 = PC_L3[p];
  int D1 = 2*l1+1, D2 = 2*l2+1, D3 = 2*l3+1;
  int n = D1*D2*D3;
  __shared__ double Cd[125];
  __shared__ double Re[125], Im[125];
  __shared__ double sel[2];
  int t = threadIdx.x;
  if (t < n){
    int i = t/(D2*D3); int rem = t - i*(D2*D3);
    int k = rem/D3; int m = rem - k*D3;
    Cd[t] = cg_coef(l1, i-l1, l2, k-l2, l3, m-l3) / sqrt((double)(2*l3+1));
  }
  __syncthreads();
  if (t < n){
    int j = t/(D2*D3); int rem = t - j*(D2*D3);
    int l = rem/D3; int m = rem - l*D3;
    double sre=0.0, sim=0.0;
    for (int i=0;i<D1;i++)
      for (int k=0;k<D2;k++)
        for (int nn=0;nn<D3;nn++){
          double c = Cd[(i*D2+k)*D3+nn];
          if (c == 0.0) continue;
          double q1r,q1i,q2r,q2i,q3r,q3i;
          qval(l1,i,j,q1r,q1i);
          qval(l2,k,l,q2r,q2i);
          qval(l3,m,nn,q3r,q3i);
          q3i = -q3i;                       // conj
          double pr = q1r*q2r - q1i*q2i;
          double pi = q1r*q2i + q1i*q2r;
          double rr = pr*q3r - pi*q3i;
          double ri = pr*q3i + pi*q3r;
          sre += rr*c; sim += ri*c;
        }
    Re[t]=sre; Im[t]=sim;
  }
  __syncthreads();
  if (t == 0){
    double nr=0.0, ni=0.0;
    for (int a=0;a<n;a++){ nr += Re[a]*Re[a]; ni += Im[a]*Im[a]; }
    sel[0] = (nr >= ni) ? 1.0 : 0.0;
    sel[1] = 1.0 / sqrt((nr >= ni) ? nr : ni);
  }
  __syncthreads();
  if (t < n){
    double v = (sel[0] != 0.0 ? Re[t] : Im[t]) * sel[1];
    w3jbuf[PC_W3J[p] + t] = (float)v;
  }
}

// ------------------------- K1: W3 transpose + b3 ---------------------------
__global__ void prep_w3r(const float* __restrict__ W3, const float* __restrict__ b3,
                         float* __restrict__ W3R){
  int idx = blockIdx.x*256 + threadIdx.x;
  if (idx >= 3456*E_PADC) return;
  int col = idx / E_PADC, c = idx - col*E_PADC;
  float v = 0.f;
  if (c < 64)      v = W3[c*3456 + col];
  else if (c == 64) v = b3[col];
  W3R[idx] = v;
}

// ------------------------- K2: radial MLP ----------------------------------
__global__ __launch_bounds__(256) void mlp_kernel(
    const float* __restrict__ radial, const float* __restrict__ W1,
    const float* __restrict__ b1, const float* __restrict__ W2,
    const float* __restrict__ b2, float* __restrict__ h2T, int E){
  __shared__ float W1s[8*64], W2s[64*64], b1s[64], b2s[64];
  for (int i = threadIdx.x; i < 512; i += 256) W1s[i] = W1[i];
  for (int i = threadIdx.x; i < 4096; i += 256) W2s[i] = W2[i];
  if (threadIdx.x < 64){ b1s[threadIdx.x]=b1[threadIdx.x]; b2s[threadIdx.x]=b2[threadIdx.x]; }
  __syncthreads();
  int e = blockIdx.x*256 + threadIdx.x;
  if (e >= E) return;
  const float4* rr = (const float4*)(radial + (size_t)e*8);
  float4 v0 = rr[0], v1 = rr[1];
  float r[8] = {v0.x,v0.y,v0.z,v0.w,v1.x,v1.y,v1.z,v1.w};
  float h1[64];
#pragma unroll
  for (int c=0;c<64;c++){
    float s = b1s[c];
#pragma unroll
    for (int j=0;j<8;j++) s += r[j]*W1s[j*64+c];
    h1[c] = s / (1.f + __expf(-s));
  }
  for (int c4=0;c4<64;c4+=4){
    float s0=b2s[c4], s1=b2s[c4+1], s2=b2s[c4+2], s3=b2s[c4+3];
#pragma unroll
    for (int j=0;j<64;j++){
      float4 wv = *(const float4*)&W2s[j*64+c4];
      s0 += h1[j]*wv.x; s1 += h1[j]*wv.y; s2 += h1[j]*wv.z; s3 += h1[j]*wv.w;
    }
    h2T[(size_t)(c4+0)*E + e] = s0/(1.f+__expf(-s0));
    h2T[(size_t)(c4+1)*E + e] = s1/(1.f+__expf(-s1));
    h2T[(size_t)(c4+2)*E + e] = s2/(1.f+__expf(-s2));
    h2T[(size_t)(c4+3)*E + e] = s3/(1.f+__expf(-s3));
  }
}

// ------------------------- K3: fused TP edge kernel ------------------------
template<int P, int WLO, int WHI>
__device__ __forceinline__ void run_path(const float* __restrict__ W3R,
                                         const float* __restrict__ w3j,
                                         const float (&h2r)[64], int lane,
                                         const float (*xs)[64],
                                         const float (*shs)[64],
                                         float (*accb)[64])
{
  constexpr int i1 = pt::I1[P], i2 = pt::I2[P], i3 = pt::I3[P];
  constexpr int D1 = 2*i1+1, D2 = 2*i2+1, D3 = 2*i3+1;
  constexpr int M1 = pt::MUL[i1], M3 = pt::MUL[i3];
  constexpr int FO = pt::FOF[i1], SO = pt::SOF[i2], OO = pt::OOF[i3];
  constexpr int COLOFF = pt::COL[P];
  constexpr int W3JO = pt::W3JO[P];
  constexpr float COEF = (i3==0) ? 0.13363062095621219f     // sqrt(1/56)
                        : (i3==1) ? 0.20412414523193150f    // sqrt(3/72)
                                  : 0.27950849718747373f;   // sqrt(5/64)
  // Pm[i][k] = COEF * sum_j sh[j] * C[i][j][k]
  float Pm[D1][D3];
#pragma unroll
  for (int i=0;i<D1;i++)
#pragma unroll
    for (int k=0;k<D3;k++) Pm[i][k] = 0.f;
#pragma unroll
  for (int j=0;j<D2;j++){
    float shv = shs[SO+j][lane];
#pragma unroll
    for (int i=0;i<D1;i++)
#pragma unroll
      for (int k=0;k<D3;k++)
        Pm[i][k] += shv * w3j[W3JO + (i*D2+j)*D3 + k];
  }
#pragma unroll
  for (int i=0;i<D1;i++)
#pragma unroll
    for (int k=0;k<D3;k++) Pm[i][k] *= COEF;

#pragma unroll 1
  for (int u=0; u<M1; ++u){
    float xv[D1];
#pragma unroll
    for (int i=0;i<D1;i++) xv[i] = xs[FO + u*D1 + i][lane];
    float tv[D3];
#pragma unroll
    for (int k=0;k<D3;k++){
      float s = 0.f;
#pragma unroll
      for (int i=0;i<D1;i++) s += xv[i]*Pm[i][k];
      tv[k] = s;
    }
    // wave-uniform pointer (no threadIdx taint) -> scalar loads
    const float* base = W3R + (COLOFF + u*M3 + WLO)*E_PADC;
#pragma unroll 1
    for (int w=WLO; w<WHI; w+=2){
      const float* pa = base; const float* pb = base + E_PADC;
      base += 2*E_PADC;
      float a0=0.f,a1=0.f,b0=0.f,b1=0.f,c0=0.f,c1=0.f,d0=0.f,d1=0.f;
#pragma unroll
      for (int c=0;c<64;c+=4){
        a0 += h2r[c+0]*pa[c+0];  a1 += h2r[c+0]*pb[c+0];
        b0 += h2r[c+1]*pa[c+1];  b1 += h2r[c+1]*pb[c+1];
        c0 += h2r[c+2]*pa[c+2];  c1 += h2r[c+2]*pb[c+2];
        d0 += h2r[c+3]*pa[c+3];  d1 += h2r[c+3]*pb[c+3];
      }
      float wp0 = ((a0+b0)+(c0+d0)) + pa[64];
      float wp1 = ((a1+b1)+(c1+d1)) + pb[64];
#pragma unroll
      for (int k=0;k<D3;k++){
        accb[OO + (w+0)*D3 + k][lane] += wp0*tv[k];
        accb[OO + (w+1)*D3 + k][lane] += wp1*tv[k];
      }
    }
  }
}

__global__ __launch_bounds__(256,2) void edge_kernel(
    const int* __restrict__ eidx, const float* __restrict__ nf,
    const float* __restrict__ esh, const float* __restrict__ h2T,
    const float* __restrict__ W3R, const float* __restrict__ w3jbuf,
    float* __restrict__ agg, int E){
  __shared__ float xs[120][64];
  __shared__ float shs[9][64];
  __shared__ float accb[120][64];
  __shared__ int srcS[64], dstS[64];
  int tid = threadIdx.x, lane = tid & 63, wv = tid >> 6;
  int ebase = blockIdx.x * 64;

  if (tid < 64){
    int e = min(ebase + tid, E-1);
    srcS[tid] = eidx[e];
    dstS[tid] = eidx[E + e];
  }
  for (int i = tid; i < 120*64; i += 256) ((float*)accb)[i] = 0.f;
  for (int i = tid; i < 576; i += 256){
    int e = i/9, j = i - e*9;
    int ge = min(ebase + e, E-1);
    shs[j][e] = esh[(size_t)ge*9 + j];
  }
  __syncthreads();
  {
    int s = srcS[lane];
    const float4* row = (const float4*)(nf + (size_t)s*120);
    for (int d4 = wv; d4 < 30; d4 += 4){
      float4 v = row[d4];
      xs[d4*4+0][lane]=v.x; xs[d4*4+1][lane]=v.y;
      xs[d4*4+2][lane]=v.z; xs[d4*4+3][lane]=v.w;
    }
  }
  float h2r[64];
  {
    int eg = min(ebase + lane, E-1);
#pragma unroll
    for (int c=0;c<64;c++) h2r[c] = h2T[(size_t)c*E + eg];
  }
  __syncthreads();

  // disjoint output-slot partition -> no atomics in LDS
  if (wv == 0){
    run_path<0,0,16>(W3R,w3jbuf,h2r,lane,xs,shs,accb);
    run_path<4,0,16>(W3R,w3jbuf,h2r,lane,xs,shs,accb);
    run_path<9,0,16>(W3R,w3jbuf,h2r,lane,xs,shs,accb);
  } else if (wv == 1){
    run_path<0,16,32>(W3R,w3jbuf,h2r,lane,xs,shs,accb);
    run_path<4,16,32>(W3R,w3jbuf,h2r,lane,xs,shs,accb);
    run_path<9,16,32>(W3R,w3jbuf,h2r,lane,xs,shs,accb);
  } else if (wv == 2){
    run_path<1,0,12>(W3R,w3jbuf,h2r,lane,xs,shs,accb);
    run_path<3,0,12>(W3R,w3jbuf,h2r,lane,xs,shs,accb);
    run_path<6,0,12>(W3R,w3jbuf,h2r,lane,xs,shs,accb);
    run_path<8,0,12>(W3R,w3jbuf,h2r,lane,xs,shs,accb);
  } else {
    run_path<1,12,16>(W3R,w3jbuf,h2r,lane,xs,shs,accb);
    run_path<3,12,16>(W3R,w3jbuf,h2r,lane,xs,shs,accb);
    run_path<6,12,16>(W3R,w3jbuf,h2r,lane,xs,shs,accb);
    run_path<8,12,16>(W3R,w3jbuf,h2r,lane,xs,shs,accb);
    run_path<2,0,8>(W3R,w3jbuf,h2r,lane,xs,shs,accb);
    run_path<5,0,8>(W3R,w3jbuf,h2r,lane,xs,shs,accb);
    run_path<7,0,8>(W3R,w3jbuf,h2r,lane,xs,shs,accb);
    run_path<10,0,8>(W3R,w3jbuf,h2r,lane,xs,shs,accb);
  }
  __syncthreads();

  // scatter: thread (lane=e, wv=quarter) -> 30 slots
  {
    int ge = ebase + lane;
    if (ge < E){
      float* arow = agg + (size_t)dstS[lane]*120;
      for (int s2 = wv*30; s2 < wv*30+30; ++s2)
        unsafeAtomicAdd(&arow[s2], accb[s2][lane]);
    }
  }
}

// ------------------------- K4: node linear + residual ----------------------
__global__ void out_kernel(const float* __restrict__ agg, const float* __restrict__ nf,
                           const float* __restrict__ Ws0, const float* __restrict__ Ws1,
                           const float* __restrict__ Ws2, float* __restrict__ out, int N){
  int idx = blockIdx.x*256 + threadIdx.x;
  if (idx >= N*120) return;
  int n = idx/120, slot = idx - n*120;
  const float* arow = agg + (size_t)n*120;
  float s;
  if (slot < 32){
    float acc = 0.f;
#pragma unroll
    for (int u=0;u<32;u++) acc += arow[u]*Ws0[u*32+slot];
    s = acc * 0.17677669529663687f;        // 1/sqrt(32)
  } else if (slot < 80){
    int r = slot-32; int v = r/3, d = r - v*3;
    float acc = 0.f;
#pragma unroll
    for (int u=0;u<16;u++) acc += arow[32 + u*3 + d]*Ws1[u*16+v];
    s = acc * 0.25f;                       // 1/sqrt(16)
  } else {
    int r = slot-80; int v = r/5, d = r - v*5;
    float acc = 0.f;
#pragma unroll
    for (int u=0;u<8;u++) acc += arow[80 + u*5 + d]*Ws2[u*8+v];
    s = acc * 0.35355339059327373f;        // 1/sqrt(8)
  }
  out[idx] = s + nf[idx];
}

// ------------------------- host launch -------------------------------------
extern "C" void kernel_launch(void* const* d_in, const int* in_sizes, int n_in,
                              void* d_out, int out_size, void* d_ws, size_t ws_size,
                              hipStream_t stream) {
  const float* nf     = (const float*)d_in[0];
  const int*   eidx   = (const int*)  d_in[1];
  const float* esh    = (const float*)d_in[2];
  const float* radial = (const float*)d_in[3];
  const float* W1     = (const float*)d_in[4];
  const float* b1     = (const float*)d_in[5];
  const float* W2     = (const float*)d_in[6];
  const float* b2     = (const float*)d_in[7];
  const float* W3     = (const float*)d_in[8];
  const float* b3     = (const float*)d_in[9];
  const float* Ws0    = (const float*)d_in[10];
  const float* Ws1    = (const float*)d_in[11];
  const float* Ws2    = (const float*)d_in[12];
  float* out = (float*)d_out;

  int N = in_sizes[0] / 120;
  int E = in_sizes[1] / 2;

  float* w3jbuf = (float*)d_ws;                         // 363 floats (reserve 1024)
  float* W3R    = (float*)d_ws + 1024;                  // 3456*68 floats
  float* h2T    = W3R + 3456*E_PADC;                    // 64*E floats
  float* agg    = h2T + (size_t)64*E;                   // N*120 floats

  w3j_kernel<<<11, 128, 0, stream>>>(w3jbuf);
  prep_w3r<<<(3456*E_PADC + 255)/256, 256, 0, stream>>>(W3, b3, W3R);
  mlp_kernel<<<(E + 255)/256, 256, 0, stream>>>(radial, W1, b1, W2, b2, h2T, E);
  hipMemsetAsync(agg, 0, (size_t)N*120*sizeof(float), stream);
  edge_kernel<<<(E + 63)/64, 256, 0, stream>>>(eidx, nf, esh, h2T, W3R, w3jbuf, agg, E);
  out_kernel<<<(N*120 + 255)/256, 256, 0, stream>>>(agg, nf, Ws0, Ws1, Ws2, out, N);
}